// Round 5
// baseline (624.959 us; speedup 1.0000x reference)
//
#include <hip/hip_runtime.h>
#include <hip/hip_bf16.h>

// B=32, S=2048, H=1024, U=1024. M = B*S = 65536 rows.
// score[b,s] = sum_u tanh(enc[b,s,:]@W1[:,u] + W1b[u] + ph[b,u]) * Vw[u]  (+Vb cancels in softmax)
// out = softmax_s(score)

typedef __bf16 bf16x8 __attribute__((ext_vector_type(8)));
typedef float  f32x4  __attribute__((ext_vector_type(4)));

#define HDIM 1024
#define UDIM 1024
#define SDIM 2048
#define MROWS 65536
#define BM 128
#define BN 128
#define BK 64    // R5: 32->64 — halves barrier-drain events per unit K

__device__ inline unsigned short f2bf(float x) {
    return __builtin_bit_cast(unsigned short, (__bf16)x);
}

// fast tanh: tanh(x) = sign(x) * (1-e^{-2|x|})/(1+e^{-2|x|}). z in (0,1].
__device__ inline float fast_tanh(float x) {
    float z = __expf(-2.0f * __builtin_fabsf(x));
    float t = __fdividef(1.0f - z, 1.0f + z);
    return __builtin_copysignf(t, x);
}

// async 16B global->LDS (m97: width=16 emits global_load_lds_dwordx4)
#define GLDS16(gp, lp)                                                              \
    __builtin_amdgcn_global_load_lds(                                               \
        (const __attribute__((address_space(1))) unsigned int*)(gp),                \
        (__attribute__((address_space(3))) unsigned int*)(lp), 16, 0, 0)

// ---------------- prep: enc fp32 -> bf16 (pure BW pass) ----------------
__global__ __launch_bounds__(256) void cvt_kernel(const float* __restrict__ in,
                                                  unsigned short* __restrict__ out) {
    size_t i = ((size_t)blockIdx.x * 256 + threadIdx.x) * 8;
    const float4 f0 = *(const float4*)(in + i);
    const float4 f1 = *(const float4*)(in + i + 4);
    ushort4 h0, h1;
    h0.x = f2bf(f0.x); h0.y = f2bf(f0.y); h0.z = f2bf(f0.z); h0.w = f2bf(f0.w);
    h1.x = f2bf(f1.x); h1.y = f2bf(f1.y); h1.z = f2bf(f1.z); h1.w = f2bf(f1.w);
    *(ushort4*)(out + i) = h0;
    *(ushort4*)(out + i + 4) = h1;
}

// ---------------- prep: W1 [H,U] fp32 -> W1T [U,H] bf16 ----------------
__global__ void w1t_kernel(const float* __restrict__ W1, unsigned short* __restrict__ W1T) {
    __shared__ float tile[32][33];
    int bx = blockIdx.x;   // u tile
    int by = blockIdx.y;   // h tile
    int tx = threadIdx.x, ty = threadIdx.y;   // (32,8)
#pragma unroll
    for (int r = 0; r < 4; ++r) {
        int h = by * 32 + ty + r * 8;
        int u = bx * 32 + tx;
        tile[ty + r * 8][tx] = W1[h * UDIM + u];
    }
    __syncthreads();
#pragma unroll
    for (int r = 0; r < 4; ++r) {
        int u = bx * 32 + ty + r * 8;
        int h = by * 32 + tx;
        W1T[u * HDIM + h] = f2bf(tile[tx][ty + r * 8]);
    }
}

// ---------------- prep: ph partials (split-K over h) ----------------
__global__ void php_kernel(const float* __restrict__ hn, const float* __restrict__ W2,
                           float* __restrict__ php) {
    int u = (blockIdx.x & 3) * 256 + threadIdx.x;
    int b = blockIdx.y;
    int hc = blockIdx.z;           // 8 chunks of 128
    int h0 = hc * 128;
    float acc = 0.f;
#pragma unroll 8
    for (int h = h0; h < h0 + 128; ++h)
        acc = fmaf(hn[b * HDIM + h], W2[h * UDIM + u], acc);
    php[(hc * 32 + b) * UDIM + u] = acc;
}

__global__ void ph_combine(const float* __restrict__ php, const float* __restrict__ W1b,
                           const float* __restrict__ W2b, float* __restrict__ ph) {
    int idx = blockIdx.x * 256 + threadIdx.x;   // 32768
    int u = idx & (UDIM - 1);
    int b = idx >> 10;
    float acc = W1b[u] + W2b[u];
#pragma unroll
    for (int p = 0; p < 8; ++p) acc += php[(p * 32 + b) * UDIM + u];
    ph[idx] = acc;
}

// ---------------- main fused GEMM (async staging, BK=64, XOR-swizzled LDS) ----------------
// LDS: 8 16B-chunks per row (BK=64). Physical chunk slot (row, p) holds logical kchunk
//   klog = p ^ (row&7). Staging chunk index c = issue*256 + wid*64 + lane -> row = c>>3,
//   slot p = c&7, global kchunk = (c&7)^((c>>3)&7): a bijective 16B permutation inside each
//   row's 128B window -> coalescing intact, global_load_lds-legal (dest = base + lane*16).
// Fragment read (k-step s): logical chunk s*4+(lane>>4) at phys (s*4+(lane>>4))^(mrow&7)
//   -> uniform quad-bank spread, 0 conflicts (verified R4 pattern, generalized mod 8).
__global__ __launch_bounds__(256) void score_kernel(
    const unsigned short* __restrict__ encb, const unsigned short* __restrict__ W1T,
    const float* __restrict__ ph, const float* __restrict__ Vw,
    float* __restrict__ part) {
    __shared__ unsigned short As[BM * BK];   // 16384 B
    __shared__ unsigned short Bs[BN * BK];   // 16384 B

    const int bx = blockIdx.x;
    // XCD swizzle: bx&7 -> XCD; each XCD owns a 64-tile m-slab, n-fastest inside.
    const int x = bx & 7;
    const int k = bx >> 3;
    const int tile_n = k & 7;
    const int tile_m = (x << 6) | (k >> 3);

    const int t = threadIdx.x;
    const int lane = t & 63;
    const int wid = t >> 6;
    const int wm = wid >> 1, wn = wid & 1;

    const int row0 = tile_m * BM;
    const int col0 = tile_n * BN;

    f32x4 acc[4][4];
#pragma unroll
    for (int i = 0; i < 4; ++i)
#pragma unroll
        for (int j = 0; j < 4; ++j)
            acc[i][j] = (f32x4){0.f, 0.f, 0.f, 0.f};

    const int mrow = lane & 15;
    const int swz = mrow & 7;              // row&7 for all fragment rows (wm*64+i*16 ≡ 0 mod 8)
    const int kgrp = lane >> 4;            // 0..3

    // staging: 4 issues per buffer; chunk c = issue*256 + wid*64 + lane
    const int cI = wid * 64 + lane;
    int rS[4], klS[4];
#pragma unroll
    for (int issue = 0; issue < 4; ++issue) {
        int c = cI + issue * 256;
        rS[issue] = c >> 3;
        klS[issue] = ((c & 7) ^ ((c >> 3) & 7)) * 8;   // element offset of logical kchunk
    }

    for (int kt = 0; kt < HDIM; kt += BK) {
#pragma unroll
        for (int issue = 0; issue < 4; ++issue) {
            const unsigned short* ga = encb + (size_t)(row0 + rS[issue]) * HDIM + kt + klS[issue];
            GLDS16(ga, (char*)As + (unsigned)(issue * 256 + wid * 64) * 16);
        }
#pragma unroll
        for (int issue = 0; issue < 4; ++issue) {
            const unsigned short* gb = W1T + (size_t)(col0 + rS[issue]) * HDIM + kt + klS[issue];
            GLDS16(gb, (char*)Bs + (unsigned)(issue * 256 + wid * 64) * 16);
        }
        __syncthreads();   // drains vmcnt; LDS tile visible

#pragma unroll
        for (int s = 0; s < 2; ++s) {
            const int phys = ((s * 4 + kgrp) ^ swz) * 8;   // element offset
            bf16x8 a[4], bb[4];
#pragma unroll
            for (int i = 0; i < 4; ++i)
                a[i] = *reinterpret_cast<const bf16x8*>(As + (wm * 64 + i * 16 + mrow) * BK + phys);
#pragma unroll
            for (int j = 0; j < 4; ++j)
                bb[j] = *reinterpret_cast<const bf16x8*>(Bs + (wn * 64 + j * 16 + mrow) * BK + phys);
#pragma unroll
            for (int i = 0; i < 4; ++i)
#pragma unroll
                for (int j = 0; j < 4; ++j)
                    acc[i][j] = __builtin_amdgcn_mfma_f32_16x16x32_bf16(a[i], bb[j], acc[i][j], 0, 0, 0);
        }
        __syncthreads();   // all waves done reading before next stage overwrites
    }

    // epilogue: +ph -> fast_tanh -> *Vw -> reduce over u cols -> partial slice
    const int b = row0 >> 11;          // S=2048 rows per batch; BM divides S
    const int colg = lane & 15;        // C/D: col = lane&15
    const int rowq = (lane >> 4) * 4;  // C/D: row = quad*4 + reg
    float vw[4], phv[4];
#pragma unroll
    for (int j = 0; j < 4; ++j) {
        int u = col0 + wn * 64 + j * 16 + colg;
        vw[j] = Vw[u];
        phv[j] = ph[b * UDIM + u];
    }
#pragma unroll
    for (int i = 0; i < 4; ++i) {
#pragma unroll
        for (int r = 0; r < 4; ++r) {
            float s = 0.f;
#pragma unroll
            for (int j = 0; j < 4; ++j) {
                float pe = acc[i][j][r] + phv[j];
                s += fast_tanh(pe) * vw[j];
            }
            s += __shfl_xor(s, 1);
            s += __shfl_xor(s, 2);
            s += __shfl_xor(s, 4);
            s += __shfl_xor(s, 8);
            if (colg == 0) {
                int row = row0 + wm * 64 + i * 16 + rowq + r;
                part[(size_t)(tile_n * 2 + wn) * MROWS + row] = s;
            }
        }
    }
}

// ---------------- fallback GEMM (fp32 in-register convert, BK=32) ----------------
#define LDK 40
#define FBK 32
__global__ __launch_bounds__(256) void score_kernel_f32(
    const float* __restrict__ enc, const unsigned short* __restrict__ W1T,
    const float* __restrict__ ph, const float* __restrict__ Vw,
    float* __restrict__ part) {
    __shared__ unsigned short As[BM * LDK];
    __shared__ unsigned short Bs[BN * LDK];

    const int bx = blockIdx.x;
    const int tile_n = bx & 7;
    const int tile_m = bx >> 3;
    const int t = threadIdx.x;
    const int lane = t & 63;
    const int wid = t >> 6;
    const int wm = wid >> 1, wn = wid & 1;

    const int row0 = tile_m * BM;
    const int col0 = tile_n * BN;

    f32x4 acc[4][4];
#pragma unroll
    for (int i = 0; i < 4; ++i)
#pragma unroll
        for (int j = 0; j < 4; ++j)
            acc[i][j] = (f32x4){0.f, 0.f, 0.f, 0.f};

    const int mrow = lane & 15;
    const int kq = (lane >> 4) * 8;

    for (int kt = 0; kt < HDIM; kt += FBK) {
        __syncthreads();
#pragma unroll
        for (int i = 0; i < 4; ++i) {
            int c = t + 256 * i;
            int r = c >> 3;
            int kc = (c & 7) * 4;
            const float4 f = *(const float4*)(enc + (size_t)(row0 + r) * HDIM + kt + kc);
            ushort4 h;
            h.x = f2bf(f.x); h.y = f2bf(f.y); h.z = f2bf(f.z); h.w = f2bf(f.w);
            *(ushort4*)(As + r * LDK + kc) = h;
        }
#pragma unroll
        for (int i = 0; i < 2; ++i) {
            int c = t + 256 * i;
            int r = c >> 2;
            int kc = (c & 3) * 8;
            const uint4 v = *(const uint4*)(W1T + (size_t)(col0 + r) * HDIM + kt + kc);
            *(uint4*)(Bs + r * LDK + kc) = v;
        }
        __syncthreads();

        bf16x8 a[4], bb[4];
#pragma unroll
        for (int i = 0; i < 4; ++i)
            a[i] = *reinterpret_cast<const bf16x8*>(As + (wm * 64 + i * 16 + mrow) * LDK + kq);
#pragma unroll
        for (int j = 0; j < 4; ++j)
            bb[j] = *reinterpret_cast<const bf16x8*>(Bs + (wn * 64 + j * 16 + mrow) * LDK + kq);
#pragma unroll
        for (int i = 0; i < 4; ++i)
#pragma unroll
            for (int j = 0; j < 4; ++j)
                acc[i][j] = __builtin_amdgcn_mfma_f32_16x16x32_bf16(a[i], bb[j], acc[i][j], 0, 0, 0);
    }

    const int b = row0 >> 11;
    const int colg = lane & 15;
    const int rowq = (lane >> 4) * 4;
    float vw[4], phv[4];
#pragma unroll
    for (int j = 0; j < 4; ++j) {
        int u = col0 + wn * 64 + j * 16 + colg;
        vw[j] = Vw[u];
        phv[j] = ph[b * UDIM + u];
    }
#pragma unroll
    for (int i = 0; i < 4; ++i) {
#pragma unroll
        for (int r = 0; r < 4; ++r) {
            float s = 0.f;
#pragma unroll
            for (int j = 0; j < 4; ++j) {
                float pe = acc[i][j][r] + phv[j];
                s += fast_tanh(pe) * vw[j];
            }
            s += __shfl_xor(s, 1);
            s += __shfl_xor(s, 2);
            s += __shfl_xor(s, 4);
            s += __shfl_xor(s, 8);
            if (colg == 0) {
                int row = row0 + wm * 64 + i * 16 + rowq + r;
                part[(size_t)(tile_n * 2 + wn) * MROWS + row] = s;
            }
        }
    }
}

// ---------------- final: sum 16 partial slices + softmax over s ----------------
__global__ void softmax_kernel(const float* __restrict__ part, float* __restrict__ out) {
    int b = blockIdx.x;
    int t = threadIdx.x;   // 256
    __shared__ float sred[4];
    float v[8];
    float lmax = -3.4e38f;
#pragma unroll
    for (int i = 0; i < 8; ++i) {
        int s = t + i * 256;
        float sum = 0.f;
#pragma unroll
        for (int p = 0; p < 16; ++p) sum += part[(size_t)p * MROWS + b * SDIM + s];
        v[i] = sum;
        lmax = fmaxf(lmax, sum);
    }
#pragma unroll
    for (int off = 1; off < 64; off <<= 1) lmax = fmaxf(lmax, __shfl_xor(lmax, off));
    if ((t & 63) == 0) sred[t >> 6] = lmax;
    __syncthreads();
    float bmax = fmaxf(fmaxf(sred[0], sred[1]), fmaxf(sred[2], sred[3]));
    __syncthreads();
    float lsum = 0.f;
#pragma unroll
    for (int i = 0; i < 8; ++i) {
        v[i] = expf(v[i] - bmax);
        lsum += v[i];
    }
#pragma unroll
    for (int off = 1; off < 64; off <<= 1) lsum += __shfl_xor(lsum, off);
    if ((t & 63) == 0) sred[t >> 6] = lsum;
    __syncthreads();
    float inv = 1.0f / (sred[0] + sred[1] + sred[2] + sred[3]);
#pragma unroll
    for (int i = 0; i < 8; ++i) out[b * SDIM + t + i * 256] = v[i] * inv;
}

extern "C" void kernel_launch(void* const* d_in, const int* in_sizes, int n_in,
                              void* d_out, int out_size, void* d_ws, size_t ws_size,
                              hipStream_t stream) {
    const float* enc = (const float*)d_in[0];
    const float* hn  = (const float*)d_in[1];
    const float* W1  = (const float*)d_in[2];
    const float* W1b = (const float*)d_in[3];
    const float* W2  = (const float*)d_in[4];
    const float* W2b = (const float*)d_in[5];
    const float* Vw  = (const float*)d_in[6];
    // d_in[7] = V_b: softmax is shift-invariant per batch -> exactly cancels.
    float* out = (float*)d_out;

    char* ws = (char*)d_ws;
    const size_t ENCB_BYTES = (size_t)MROWS * HDIM * 2;        // 128 MB
    const size_t NEED = ENCB_BYTES + (2u << 20) + (128u << 10) + (1u << 20) + (4u << 20);

    if (ws_size >= NEED) {
        unsigned short* encb = (unsigned short*)ws;                                  // 128 MB
        unsigned short* W1T  = (unsigned short*)(ws + ENCB_BYTES);                   // 2 MB
        float* ph   = (float*)(ws + ENCB_BYTES + (2u << 20));                        // 128 KB
        float* php  = (float*)(ws + ENCB_BYTES + (2u << 20) + (128u << 10));         // 1 MB
        float* part = (float*)(ws + ENCB_BYTES + (2u << 20) + (128u << 10) + (1u << 20)); // 4 MB

        cvt_kernel<<<32768, 256, 0, stream>>>(enc, encb);
        w1t_kernel<<<dim3(32, 32), dim3(32, 8), 0, stream>>>(W1, W1T);
        php_kernel<<<dim3(4, 32, 8), 256, 0, stream>>>(hn, W2, php);
        ph_combine<<<128, 256, 0, stream>>>(php, W1b, W2b, ph);
        score_kernel<<<dim3(4096), 256, 0, stream>>>(encb, W1T, ph, Vw, part);
        softmax_kernel<<<32, 256, 0, stream>>>(part, out);
    } else {
        unsigned short* W1T = (unsigned short*)ws;
        float* ph   = (float*)(ws + (2u << 20));
        float* php  = (float*)(ws + (2u << 20) + (128u << 10));
        float* part = (float*)(ws + (2u << 20) + (128u << 10) + (1u << 20));

        w1t_kernel<<<dim3(32, 32), dim3(32, 8), 0, stream>>>(W1, W1T);
        php_kernel<<<dim3(4, 32, 8), 256, 0, stream>>>(hn, W2, php);
        ph_combine<<<128, 256, 0, stream>>>(php, W1b, W2b, ph);
        score_kernel_f32<<<dim3(4096), 256, 0, stream>>>(enc, W1T, ph, Vw, part);
        softmax_kernel<<<32, 256, 0, stream>>>(part, out);
    }
}